// Round 8
// baseline (260.959 us; speedup 1.0000x reference)
//
#include <hip/hip_runtime.h>
#include <math.h>

// MSTAGNN: N nodes, E edges (propagation), FE full edges (regression head).
// HC=64, HEADS=4, HEADC=DV=16, KHOP=3, NUM_T=128.
// R14 = R13 with hop 0 ported into the high-occupancy dense structure
// (2 nodes/block, 128 thr/node, 32 VGPR, 67% occ — R13-verified) as a
// template MODE: MODE 0 gathers Kf'(2B)+V(16B) per thread per edge and forms
// the outer product in-register; MODE 1 is the unchanged dense fp8-M gather.
// Dense hops measured pinned at the ~2 TB/s scattered-miss wall (84 MB/hop,
// 6 structures tried) — untouched.

#define HC 64
#define HEADS 4
#define KHOP 3
#define NUM_T 128
#define MSZ 1024    // bytes per node M row (fp8)
#define SLOTS 64    // padded CSR slots per node
#define CST 1e-5f

typedef float f32x2 __attribute__((ext_vector_type(2)));

// ---- bf16 helpers (storage-only precision; accumulate in fp32) ----
__device__ __forceinline__ float bf2f(unsigned short s) { return __uint_as_float(((unsigned int)s) << 16); }
__device__ __forceinline__ float bfu_lo(unsigned int u) { return __uint_as_float(u << 16); }
__device__ __forceinline__ float bfu_hi(unsigned int u) { return __uint_as_float(u & 0xffff0000u); }
__device__ __forceinline__ unsigned short f2bf(float f) {
    unsigned int u = __float_as_uint(f);
    u = (u + 0x7fffu + ((u >> 16) & 1u)) >> 16;   // RTNE
    return (unsigned short)u;
}
// ---- fp8 e4m3 via HW pack/unpack (gfx950 OCP) ----
__device__ __forceinline__ unsigned int pack4fp8(float a, float b, float c, float d) {
    int r = __builtin_amdgcn_cvt_pk_fp8_f32(a, b, 0, false);       // bytes 0,1
    r = __builtin_amdgcn_cvt_pk_fp8_f32(c, d, r, true);            // bytes 2,3
    return (unsigned int)r;
}

// ---- k_pre: blocks [0,fillBlocks) = padded-CSR fill; blocks [fillBlocks,
//      fillBlocks+NUM_T) = temb table (one tval each) + gamma (first) ----
__global__ __launch_bounds__(256) void k_pre(
    const int* __restrict__ row, const int* __restrict__ col,
    int* __restrict__ cnt, int* __restrict__ csr, int E, int fillBlocks,
    const float* __restrict__ Wt1, const float* __restrict__ bt1,
    const float* __restrict__ Wt2, const float* __restrict__ bt2,
    const float* __restrict__ hopwise, const float* __restrict__ headwise,
    float* __restrict__ gamma, float* __restrict__ table) {
    int b = blockIdx.x;
    if (b < fillBlocks) {
        int e = b * 256 + threadIdx.x;
        if (e < E) {
            int c = col[e];
            int r = row[e];
            int k = atomicAdd(&cnt[c], 1);
            if (k < SLOTS) csr[c * SLOTS + k] = r;
        }
        return;
    }
    int tval = b - fillBlocks;                       // 0..127
    int t = threadIdx.x;
    if (tval == 0 && t == 0) {
        for (int k = 0; k < KHOP; k++) {
            float m = -1e30f;
            for (int h2 = 0; h2 < HEADS; h2++) m = fmaxf(m, headwise[h2 * KHOP + k]);
            float ex[HEADS]; float s = 0.f;
            for (int h2 = 0; h2 < HEADS; h2++) { ex[h2] = expf(headwise[h2 * KHOP + k] - m); s += ex[h2]; }
            for (int h2 = 0; h2 < HEADS; h2++) gamma[k * HEADS + h2] = hopwise[k + 1] * ex[h2] / s;
        }
    }
    __shared__ float emb_s[64];
    __shared__ float z1_s[256];
    __shared__ float ps_s[4][64];
    if (t < 64) {
        float tt = (float)tval * 31.25f;             // 4000/128
        float e;
        if (t < 32) e = sinf(tt * expf(-0.2971077539347156f * (float)t));
        else        e = cosf(tt * expf(-0.2971077539347156f * (float)(t - 32)));
        emb_s[t] = e;
    }
    __syncthreads();
    {   // z1[t] = silu(emb . Wt1[:,t] + bt1[t])
        float acc = bt1[t];
        #pragma unroll 8
        for (int i = 0; i < 64; i++) acc += emb_s[i] * Wt1[i * 256 + t];
        z1_s[t] = acc / (1.f + expf(-acc));
    }
    __syncthreads();
    {   // out[j] = z1 . Wt2[:,j] + bt2[j], split over 4 partials
        int j = t & 63, p = t >> 6;
        float acc = 0.f;
        #pragma unroll 8
        for (int i = 0; i < 64; i++) acc += z1_s[p * 64 + i] * Wt2[(p * 64 + i) * 64 + j];
        ps_s[p][j] = acc;
    }
    __syncthreads();
    if (t < 64)
        table[tval * 64 + t] = ps_s[0][t] + ps_s[1][t] + ps_s[2][t] + ps_s[3][t] + bt2[t];
}

// ---- fused node kernel: h -> QKV -> Q, pre-scaled Kf0'(bf16), V(bf16),
//      hidden init. inv_deg computed from cnt in-register. ----
__global__ __launch_bounds__(256) void k_node(
    const float* __restrict__ x, const int* __restrict__ time_steps,
    const float* __restrict__ temb, const float* __restrict__ Wi,
    const float* __restrict__ bi,
    const float* __restrict__ WQ, const float* __restrict__ bQ,
    const float* __restrict__ WK, const float* __restrict__ bK,
    const float* __restrict__ WV, const float* __restrict__ bV,
    const float* __restrict__ hopwise, const int* __restrict__ cnt,
    float* __restrict__ Q, unsigned short* __restrict__ Kf0,
    unsigned short* __restrict__ Vbuf, float* __restrict__ hidden, int n) {
    __shared__ float xs[16][128];                      // 8 KB
    __shared__ float hs[16][64];                       // 4 KB
    int j = threadIdx.x & 63;
    int slot = threadIdx.x >> 6;                       // wave id
    int nbase = blockIdx.x * 16;
    int nvalid = min(16, n - nbase);
    const float4* xg = (const float4*)(x + (size_t)nbase * 128);
    float4* xs4 = (float4*)&xs[0][0];
    for (int idx = threadIdx.x; idx < nvalid * 32; idx += 256) xs4[idx] = xg[idx];
    __syncthreads();
    int nl = slot * 4;
    {
        float acc[4];
        #pragma unroll
        for (int k = 0; k < 4; k++) acc[k] = 0.f;
        #pragma unroll 8
        for (int i = 0; i < 128; i++) {
            float w = Wi[i * 64 + j];
            #pragma unroll
            for (int k = 0; k < 4; k++) acc[k] += xs[nl + k][i] * w;
        }
        float bj = bi[j];
        #pragma unroll
        for (int k = 0; k < 4; k++) {
            int node = nbase + nl + k;
            float te = (node < n) ? temb[time_steps[node] * 64 + j] : 0.f;
            hs[nl + k][j] = fmaxf(acc[k] + bj + te, 0.f);
        }
    }
    __syncthreads();
    float aq[4], ak[4], av[4];
    #pragma unroll
    for (int k = 0; k < 4; k++) { aq[k] = bQ[j]; ak[k] = bK[j]; av[k] = bV[j]; }
    #pragma unroll 4
    for (int i = 0; i < 64; i++) {
        float wq = WQ[i * 64 + j], wk = WK[i * 64 + j], wv = WV[i * 64 + j];
        #pragma unroll
        for (int k = 0; k < 4; k++) {
            float hv = hs[nl + k][i];
            aq[k] += hv * wq; ak[k] += hv * wk; av[k] += hv * wv;
        }
    }
    float h0 = hopwise[0];
    #pragma unroll
    for (int k = 0; k < 4; k++) {
        int node = nbase + nl + k;
        if (node < n) {
            float q  = 1.f + ((aq[k] > 0.f) ? aq[k] : (expf(aq[k]) - 1.f));
            float kf = 1.f + ((ak[k] > 0.f) ? ak[k] : (expf(ak[k]) - 1.f));
            int dg = min(cnt[node], SLOTS);
            float inv = (dg > 0) ? 1.0f / (float)dg : 0.0f;
            Q[(size_t)node * 64 + j] = q;
            Kf0[(size_t)node * 64 + j] = f2bf(kf * inv);       // pre-scaled Kf'
            Vbuf[(size_t)node * 64 + j] = f2bf(av[k]);
            hidden[(size_t)node * 64 + j] = av[k] * h0;
        }
    }
}

// ---- hops (R7/R13 structure): 2 nodes/block, 128 thr/node; LDS epilogue;
// low VGPR -> ~67% occupancy. Thread owns 8 fp8 output elements off=gtid*8,
// i.e. (h = gtid>>5, i = (gtid>>1)&15, jh = gtid&1).
// MODE 0 (hop 0): per edge load Kf'[s][h*16+i] (2B) + V[s][h*16+jh*8..+8]
//                 (16B) and accumulate the outer product (8 fmaf).
// MODE 1 (hops 1,2): per edge load 8 fp8 of M[s] (8B) + Kf row (gtid<64).
// write_out=1: update hidden + write M'/Kf'. write_out=0: final — fused Wo
// projection (out16) + edge-head P1/P2 factorization into Pbuf.
template<int MODE>
__global__ __launch_bounds__(256) void k_dense(
    const unsigned char* __restrict__ Mold, const unsigned short* __restrict__ Kfold,
    const unsigned short* __restrict__ Vbuf,
    const int* __restrict__ cnt, const int* __restrict__ csr,
    const float* __restrict__ Q, const float* __restrict__ gamma,
    unsigned char* __restrict__ Mnew, unsigned short* __restrict__ Kfnew,
    float* __restrict__ hidden, int hop, int write_out,
    const float* __restrict__ Wo, const float* __restrict__ bo,
    const float* __restrict__ Wf1, float* __restrict__ out16,
    float* __restrict__ Pbuf, int n) {
    int group = threadIdx.x >> 7;        // node slot within block (0/1)
    int gtid  = threadIdx.x & 127;       // thread within node group
    int node  = blockIdx.x * 2 + group;
    int off   = gtid * 8;                // this thread's 8 fp8 elements [off, off+8)
    int kfi   = gtid >> 1;               // h*16 + i   (MODE 0)
    int vbyte = ((gtid >> 5) * 16 + (gtid & 1) * 8) * 2;  // V[h, jh*8] byte off
    __shared__ float sm[2][MSZ];         // 8 KB
    __shared__ float sk[2][64];
    __shared__ float sh[2][64];
    __shared__ float so[2][16];
    bool valid = (node < n);
    float acc[8];
    #pragma unroll
    for (int t = 0; t < 8; t++) acc[t] = 0.f;
    float kacc = 0.f;
    if (valid) {
        int deg = min(cnt[node], SLOTS);
        const int* lst = csr + (size_t)node * SLOTS;
        int d = 0;
        for (; d + 4 <= deg; d += 4) {
            int s0 = lst[d + 0], s1 = lst[d + 1], s2 = lst[d + 2], s3 = lst[d + 3];
            if constexpr (MODE == 0) {
                unsigned short ka = Kfold[(size_t)s0 * 64 + kfi];
                unsigned short kb = Kfold[(size_t)s1 * 64 + kfi];
                unsigned short kc = Kfold[(size_t)s2 * 64 + kfi];
                unsigned short kd = Kfold[(size_t)s3 * 64 + kfi];
                uint4 va = *(const uint4*)((const unsigned char*)Vbuf + (size_t)s0 * 128 + vbyte);
                uint4 vb = *(const uint4*)((const unsigned char*)Vbuf + (size_t)s1 * 128 + vbyte);
                uint4 vc = *(const uint4*)((const unsigned char*)Vbuf + (size_t)s2 * 128 + vbyte);
                uint4 vd = *(const uint4*)((const unsigned char*)Vbuf + (size_t)s3 * 128 + vbyte);
                const uint4 vv[4] = {va, vb, vc, vd};
                const float kk[4] = {bf2f(ka), bf2f(kb), bf2f(kc), bf2f(kd)};
                #pragma unroll
                for (int p = 0; p < 4; p++) {
                    float kf = kk[p];
                    kacc += kf;
                    acc[0] = fmaf(kf, bfu_lo(vv[p].x), acc[0]);
                    acc[1] = fmaf(kf, bfu_hi(vv[p].x), acc[1]);
                    acc[2] = fmaf(kf, bfu_lo(vv[p].y), acc[2]);
                    acc[3] = fmaf(kf, bfu_hi(vv[p].y), acc[3]);
                    acc[4] = fmaf(kf, bfu_lo(vv[p].z), acc[4]);
                    acc[5] = fmaf(kf, bfu_hi(vv[p].z), acc[5]);
                    acc[6] = fmaf(kf, bfu_lo(vv[p].w), acc[6]);
                    acc[7] = fmaf(kf, bfu_hi(vv[p].w), acc[7]);
                }
            } else {
                uint2 m0 = *(const uint2*)(Mold + (size_t)s0 * MSZ + off);
                uint2 m1 = *(const uint2*)(Mold + (size_t)s1 * MSZ + off);
                uint2 m2 = *(const uint2*)(Mold + (size_t)s2 * MSZ + off);
                uint2 m3 = *(const uint2*)(Mold + (size_t)s3 * MSZ + off);
                float kr0 = 0.f, kr1 = 0.f, kr2 = 0.f, kr3 = 0.f;
                if (gtid < 64) {
                    kr0 = bf2f(Kfold[(size_t)s0 * 64 + gtid]);
                    kr1 = bf2f(Kfold[(size_t)s1 * 64 + gtid]);
                    kr2 = bf2f(Kfold[(size_t)s2 * 64 + gtid]);
                    kr3 = bf2f(Kfold[(size_t)s3 * 64 + gtid]);
                }
                const uint2 mm[4] = {m0, m1, m2, m3};
                #pragma unroll
                for (int p = 0; p < 4; p++) {
                    f32x2 q;
                    q = __builtin_amdgcn_cvt_pk_f32_fp8((int)mm[p].x, false); acc[0] += q.x; acc[1] += q.y;
                    q = __builtin_amdgcn_cvt_pk_f32_fp8((int)mm[p].x, true);  acc[2] += q.x; acc[3] += q.y;
                    q = __builtin_amdgcn_cvt_pk_f32_fp8((int)mm[p].y, false); acc[4] += q.x; acc[5] += q.y;
                    q = __builtin_amdgcn_cvt_pk_f32_fp8((int)mm[p].y, true);  acc[6] += q.x; acc[7] += q.y;
                }
                if (gtid < 64) kacc += (kr0 + kr1) + (kr2 + kr3);
            }
        }
        for (; d < deg; d++) {
            int s = lst[d];
            if constexpr (MODE == 0) {
                float kf = bf2f(Kfold[(size_t)s * 64 + kfi]);
                uint4 v = *(const uint4*)((const unsigned char*)Vbuf + (size_t)s * 128 + vbyte);
                kacc += kf;
                acc[0] = fmaf(kf, bfu_lo(v.x), acc[0]);
                acc[1] = fmaf(kf, bfu_hi(v.x), acc[1]);
                acc[2] = fmaf(kf, bfu_lo(v.y), acc[2]);
                acc[3] = fmaf(kf, bfu_hi(v.y), acc[3]);
                acc[4] = fmaf(kf, bfu_lo(v.z), acc[4]);
                acc[5] = fmaf(kf, bfu_hi(v.z), acc[5]);
                acc[6] = fmaf(kf, bfu_lo(v.w), acc[6]);
                acc[7] = fmaf(kf, bfu_hi(v.w), acc[7]);
            } else {
                uint2 mv = *(const uint2*)(Mold + (size_t)s * MSZ + off);
                f32x2 q;
                q = __builtin_amdgcn_cvt_pk_f32_fp8((int)mv.x, false); acc[0] += q.x; acc[1] += q.y;
                q = __builtin_amdgcn_cvt_pk_f32_fp8((int)mv.x, true);  acc[2] += q.x; acc[3] += q.y;
                q = __builtin_amdgcn_cvt_pk_f32_fp8((int)mv.y, false); acc[4] += q.x; acc[5] += q.y;
                q = __builtin_amdgcn_cvt_pk_f32_fp8((int)mv.y, true);  acc[6] += q.x; acc[7] += q.y;
                if (gtid < 64) kacc += bf2f(Kfold[(size_t)s * 64 + gtid]);
            }
        }
        // stage + optional write-out
        float4* dst = (float4*)&sm[group][off];
        dst[0] = make_float4(acc[0], acc[1], acc[2], acc[3]);
        dst[1] = make_float4(acc[4], acc[5], acc[6], acc[7]);
        if constexpr (MODE == 0) {
            if ((gtid & 1) == 0) sk[group][kfi] = kacc;
        } else {
            if (gtid < 64) sk[group][gtid] = kacc;
        }
        if (write_out) {
            float inv = (deg > 0) ? 1.0f / (float)deg : 0.0f;
            uint2 st;
            st.x = pack4fp8(acc[0] * inv, acc[1] * inv, acc[2] * inv, acc[3] * inv);
            st.y = pack4fp8(acc[4] * inv, acc[5] * inv, acc[6] * inv, acc[7] * inv);
            *(uint2*)(Mnew + (size_t)node * MSZ + off) = st;
            if constexpr (MODE == 0) {
                if ((gtid & 1) == 0) Kfnew[(size_t)node * 64 + kfi] = f2bf(kacc * inv);
            } else {
                if (gtid < 64) Kfnew[(size_t)node * 64 + gtid] = f2bf(kacc * inv);
            }
        }
    }
    __syncthreads();
    if (valid && gtid < 64) {
        int hh = gtid >> 4, j = gtid & 15;
        const float* qn = Q + (size_t)node * 64 + hh * 16;
        float C = CST, H = 0.f;
        #pragma unroll
        for (int i = 0; i < 16; i++) {
            float qv = qn[i];
            C += qv * sk[group][hh * 16 + i];
            H += qv * sm[group][hh * 256 + i * 16 + j];
        }
        float g = gamma[hop * HEADS + hh];
        float hid = hidden[(size_t)node * 64 + gtid] + g * H / C;
        if (write_out) hidden[(size_t)node * 64 + gtid] = hid;
        else sh[group][gtid] = hid;              // final hop: feed fused projection
    }
    if (!write_out) {
        __syncthreads();
        if (valid && gtid < 16) {
            float a = bo[gtid];
            #pragma unroll 8
            for (int i = 0; i < 64; i++) a += sh[group][i] * Wo[i * 16 + gtid];
            out16[(size_t)node * 16 + gtid] = a;
            so[group][gtid] = a;
        }
        __syncthreads();
        if (valid && gtid < 32) {
            int o = gtid & 15, half = gtid >> 4;
            const float* wf = Wf1 + (size_t)(half * 16) * 16 + o;
            float p = 0.f;
            #pragma unroll
            for (int i = 0; i < 16; i++) p += so[group][i] * wf[i * 16];
            Pbuf[(size_t)node * 32 + gtid] = p;  // [n][0:16]=P1(src), [16:32]=P2(dst)
        }
    }
}

// ---------------- edge regression head: z = P1[s] + P2[d] + b1 ----------------
__global__ __launch_bounds__(256) void k_edge(
    const int* __restrict__ src, const int* __restrict__ dst,
    const float* __restrict__ Pbuf,
    const float* __restrict__ bf1, const float* __restrict__ Wf2,
    const float* __restrict__ bf2,
    float* __restrict__ out, int fe) {
    __shared__ float b1[16];
    __shared__ float w2[16];
    __shared__ float b2s;
    int t = threadIdx.x;
    if (t < 16) { b1[t] = bf1[t]; w2[t] = Wf2[t]; }
    if (t == 0) b2s = bf2[0];
    __syncthreads();
    int e = blockIdx.x * 256 + t;
    if (e >= fe) return;
    int s = src[e], d = dst[e];
    const float4* p1 = (const float4*)(Pbuf + (size_t)s * 32);
    const float4* p2 = (const float4*)(Pbuf + (size_t)d * 32 + 16);
    float z[16];
    #pragma unroll
    for (int q = 0; q < 4; q++) {
        float4 a = p1[q]; float4 b = p2[q];
        z[q * 4 + 0] = a.x + b.x; z[q * 4 + 1] = a.y + b.y;
        z[q * 4 + 2] = a.z + b.z; z[q * 4 + 3] = a.w + b.w;
    }
    float acc = b2s;
    #pragma unroll
    for (int o = 0; o < 16; o++) {
        float zz = z[o] + b1[o];
        zz = zz / (1.f + expf(-zz));       // silu
        acc += zz * w2[o];
    }
    out[e] = acc;
}

extern "C" void kernel_launch(void* const* d_in, const int* in_sizes, int n_in,
                              void* d_out, int out_size, void* d_ws, size_t ws_size,
                              hipStream_t stream) {
    const float* x        = (const float*)d_in[0];
    const int*   eidx     = (const int*)d_in[1];
    const int*   feidx    = (const int*)d_in[2];
    const int*   tsteps   = (const int*)d_in[3];
    const float* Wi  = (const float*)d_in[4];
    const float* bi  = (const float*)d_in[5];
    const float* Wt1 = (const float*)d_in[6];
    const float* bt1 = (const float*)d_in[7];
    const float* Wt2 = (const float*)d_in[8];
    const float* bt2 = (const float*)d_in[9];
    const float* WQ  = (const float*)d_in[10];
    const float* bQ  = (const float*)d_in[11];
    const float* WK  = (const float*)d_in[12];
    const float* bK  = (const float*)d_in[13];
    const float* WV  = (const float*)d_in[14];
    const float* bV  = (const float*)d_in[15];
    const float* Wo  = (const float*)d_in[16];
    const float* bo  = (const float*)d_in[17];
    const float* hopwise  = (const float*)d_in[18];
    const float* headwise = (const float*)d_in[19];
    const float* Wf1 = (const float*)d_in[20];
    const float* bf1 = (const float*)d_in[21];
    const float* Wf2 = (const float*)d_in[22];
    const float* bf2 = (const float*)d_in[23];

    const int N  = in_sizes[3];
    const int E  = in_sizes[1] / 2;
    const int FE = in_sizes[2] / 2;
    const int* row = eidx;           // [0,:]
    const int* col = eidx + E;       // [1,:]
    const int* fsrc = feidx;
    const int* fdst = feidx + FE;

    // ---- workspace carve-up (256B aligned) ----
    char* ws = (char*)d_ws;
    size_t off = 0;
    auto alloc = [&](size_t bytes) -> char* {
        char* p = ws + off;
        off = (off + bytes + 255) & ~(size_t)255;
        return p;
    };
    float* gamma     = (float*)alloc(KHOP * HEADS * sizeof(float));
    int*   cnt       = (int*)alloc((size_t)N * 4);
    int*   csr       = (int*)alloc((size_t)N * SLOTS * 4);
    float* temb      = (float*)alloc((size_t)NUM_T * HC * 4);
    float* Qbuf      = (float*)alloc((size_t)N * HC * 4);
    unsigned short* Kf0  = (unsigned short*)alloc((size_t)N * HC * 2);
    unsigned short* Kf_a = (unsigned short*)alloc((size_t)N * HC * 2);
    unsigned short* Kf_b = (unsigned short*)alloc((size_t)N * HC * 2);
    unsigned short* Vbuf = (unsigned short*)alloc((size_t)N * HC * 2);
    float* hidden    = (float*)alloc((size_t)N * HC * 4);
    unsigned char* M_a = (unsigned char*)alloc((size_t)N * MSZ);
    unsigned char* M_b = (unsigned char*)alloc((size_t)N * MSZ);
    float* Pbuf      = (float*)alloc((size_t)N * 32 * 4);
    (void)ws_size;

    float* out_edges = (float*)d_out;            // [FE]
    float* out_hid16 = (float*)d_out + FE;       // [N,16]

    const int fillBlocks = (E + 255) / 256;
    const int preBlocks  = fillBlocks + NUM_T;
    const int hopBlocks  = (N + 1) / 2;

    (void)hipMemsetAsync(cnt, 0, (size_t)N * 4, stream);
    // fused: CSR fill + temb table + gamma (one dispatch)
    k_pre<<<preBlocks, 256, 0, stream>>>(row, col, cnt, csr, E, fillBlocks,
                                         Wt1, bt1, Wt2, bt2, hopwise, headwise,
                                         gamma, temb);
    k_node<<<(N + 15) / 16, 256, 0, stream>>>(x, tsteps, temb, Wi, bi,
                                              WQ, bQ, WK, bK, WV, bV, hopwise, cnt,
                                              Qbuf, Kf0, Vbuf, hidden, N);
    // hop 0 (MODE 0, outer product, high-occupancy structure): -> M_a', Kf_a'
    k_dense<0><<<hopBlocks, 256, 0, stream>>>(nullptr, Kf0, Vbuf, cnt, csr, Qbuf, gamma,
                                              M_a, Kf_a, hidden, 0, 1, Wo, bo, Wf1,
                                              out_hid16, Pbuf, N);
    // hop 1 (MODE 1, dense): M_a' -> M_b'
    k_dense<1><<<hopBlocks, 256, 0, stream>>>(M_a, Kf_a, nullptr, cnt, csr, Qbuf, gamma,
                                              M_b, Kf_b, hidden, 1, 1, Wo, bo, Wf1,
                                              out_hid16, Pbuf, N);
    // hop 2 (MODE 1, final): gather M_b', fused Wo projection + P1/P2
    k_dense<1><<<hopBlocks, 256, 0, stream>>>(M_b, Kf_b, nullptr, cnt, csr, Qbuf, gamma,
                                              M_a, Kf_a, hidden, 2, 0, Wo, bo, Wf1,
                                              out_hid16, Pbuf, N);
    k_edge<<<(FE + 255) / 256, 256, 0, stream>>>(fsrc, fdst, Pbuf, bf1, Wf2, bf2,
                                                 out_edges, FE);
}

// Round 9
// 258.076 us; speedup vs baseline: 1.0112x; 1.0112x over previous
//
#include <hip/hip_runtime.h>
#include <math.h>

// MSTAGNN: N nodes, E edges (propagation), FE full edges (regression head).
// HC=64, HEADS=4, HEADC=DV=16, KHOP=3, NUM_T=128.
// R15 = R13 (best verified: dense hops in the 2-node/block, 128-thr/node,
// 32-VGPR, ~67%-occ structure; fused final epilogue) + hop0 rebuilt with
// zero-redundancy LDS staging: per 4-edge group, coalesced 128B row loads of
// Kf'/V (one request per row per wave, no per-lane duplication — R14's MODE-0
// was request-bound from 16x-redundant V loads), outer product formed from
// LDS broadcasts. Dense hops pinned at the ~2 TB/s scattered-miss wall
// (83.4 MB/hop, 6 structures tried) — untouched.

#define HC 64
#define HEADS 4
#define KHOP 3
#define NUM_T 128
#define MSZ 1024    // bytes per node M row (fp8)
#define SLOTS 64    // padded CSR slots per node
#define CST 1e-5f

typedef float f32x2 __attribute__((ext_vector_type(2)));

// ---- bf16 helpers (storage-only precision; accumulate in fp32) ----
__device__ __forceinline__ float bf2f(unsigned short s) { return __uint_as_float(((unsigned int)s) << 16); }
__device__ __forceinline__ float bfu_lo(unsigned int u) { return __uint_as_float(u << 16); }
__device__ __forceinline__ float bfu_hi(unsigned int u) { return __uint_as_float(u & 0xffff0000u); }
__device__ __forceinline__ unsigned short f2bf(float f) {
    unsigned int u = __float_as_uint(f);
    u = (u + 0x7fffu + ((u >> 16) & 1u)) >> 16;   // RTNE
    return (unsigned short)u;
}
// ---- fp8 e4m3 via HW pack/unpack (gfx950 OCP) ----
__device__ __forceinline__ unsigned int pack4fp8(float a, float b, float c, float d) {
    int r = __builtin_amdgcn_cvt_pk_fp8_f32(a, b, 0, false);       // bytes 0,1
    r = __builtin_amdgcn_cvt_pk_fp8_f32(c, d, r, true);            // bytes 2,3
    return (unsigned int)r;
}

// ---- k_pre: blocks [0,fillBlocks) = padded-CSR fill; blocks [fillBlocks,
//      fillBlocks+NUM_T) = temb table (one tval each) + gamma (first) ----
__global__ __launch_bounds__(256) void k_pre(
    const int* __restrict__ row, const int* __restrict__ col,
    int* __restrict__ cnt, int* __restrict__ csr, int E, int fillBlocks,
    const float* __restrict__ Wt1, const float* __restrict__ bt1,
    const float* __restrict__ Wt2, const float* __restrict__ bt2,
    const float* __restrict__ hopwise, const float* __restrict__ headwise,
    float* __restrict__ gamma, float* __restrict__ table) {
    int b = blockIdx.x;
    if (b < fillBlocks) {
        int e = b * 256 + threadIdx.x;
        if (e < E) {
            int c = col[e];
            int r = row[e];
            int k = atomicAdd(&cnt[c], 1);
            if (k < SLOTS) csr[c * SLOTS + k] = r;
        }
        return;
    }
    int tval = b - fillBlocks;                       // 0..127
    int t = threadIdx.x;
    if (tval == 0 && t == 0) {
        for (int k = 0; k < KHOP; k++) {
            float m = -1e30f;
            for (int h2 = 0; h2 < HEADS; h2++) m = fmaxf(m, headwise[h2 * KHOP + k]);
            float ex[HEADS]; float s = 0.f;
            for (int h2 = 0; h2 < HEADS; h2++) { ex[h2] = expf(headwise[h2 * KHOP + k] - m); s += ex[h2]; }
            for (int h2 = 0; h2 < HEADS; h2++) gamma[k * HEADS + h2] = hopwise[k + 1] * ex[h2] / s;
        }
    }
    __shared__ float emb_s[64];
    __shared__ float z1_s[256];
    __shared__ float ps_s[4][64];
    if (t < 64) {
        float tt = (float)tval * 31.25f;             // 4000/128
        float e;
        if (t < 32) e = sinf(tt * expf(-0.2971077539347156f * (float)t));
        else        e = cosf(tt * expf(-0.2971077539347156f * (float)(t - 32)));
        emb_s[t] = e;
    }
    __syncthreads();
    {   // z1[t] = silu(emb . Wt1[:,t] + bt1[t])
        float acc = bt1[t];
        #pragma unroll 8
        for (int i = 0; i < 64; i++) acc += emb_s[i] * Wt1[i * 256 + t];
        z1_s[t] = acc / (1.f + expf(-acc));
    }
    __syncthreads();
    {   // out[j] = z1 . Wt2[:,j] + bt2[j], split over 4 partials
        int j = t & 63, p = t >> 6;
        float acc = 0.f;
        #pragma unroll 8
        for (int i = 0; i < 64; i++) acc += z1_s[p * 64 + i] * Wt2[(p * 64 + i) * 64 + j];
        ps_s[p][j] = acc;
    }
    __syncthreads();
    if (t < 64)
        table[tval * 64 + t] = ps_s[0][t] + ps_s[1][t] + ps_s[2][t] + ps_s[3][t] + bt2[t];
}

// ---- fused node kernel: h -> QKV -> Q, pre-scaled Kf0'(bf16), V(bf16),
//      hidden init. inv_deg computed from cnt in-register. ----
__global__ __launch_bounds__(256) void k_node(
    const float* __restrict__ x, const int* __restrict__ time_steps,
    const float* __restrict__ temb, const float* __restrict__ Wi,
    const float* __restrict__ bi,
    const float* __restrict__ WQ, const float* __restrict__ bQ,
    const float* __restrict__ WK, const float* __restrict__ bK,
    const float* __restrict__ WV, const float* __restrict__ bV,
    const float* __restrict__ hopwise, const int* __restrict__ cnt,
    float* __restrict__ Q, unsigned short* __restrict__ Kf0,
    unsigned short* __restrict__ Vbuf, float* __restrict__ hidden, int n) {
    __shared__ float xs[16][128];                      // 8 KB
    __shared__ float hs[16][64];                       // 4 KB
    int j = threadIdx.x & 63;
    int slot = threadIdx.x >> 6;                       // wave id
    int nbase = blockIdx.x * 16;
    int nvalid = min(16, n - nbase);
    const float4* xg = (const float4*)(x + (size_t)nbase * 128);
    float4* xs4 = (float4*)&xs[0][0];
    for (int idx = threadIdx.x; idx < nvalid * 32; idx += 256) xs4[idx] = xg[idx];
    __syncthreads();
    int nl = slot * 4;
    {
        float acc[4];
        #pragma unroll
        for (int k = 0; k < 4; k++) acc[k] = 0.f;
        #pragma unroll 8
        for (int i = 0; i < 128; i++) {
            float w = Wi[i * 64 + j];
            #pragma unroll
            for (int k = 0; k < 4; k++) acc[k] += xs[nl + k][i] * w;
        }
        float bj = bi[j];
        #pragma unroll
        for (int k = 0; k < 4; k++) {
            int node = nbase + nl + k;
            float te = (node < n) ? temb[time_steps[node] * 64 + j] : 0.f;
            hs[nl + k][j] = fmaxf(acc[k] + bj + te, 0.f);
        }
    }
    __syncthreads();
    float aq[4], ak[4], av[4];
    #pragma unroll
    for (int k = 0; k < 4; k++) { aq[k] = bQ[j]; ak[k] = bK[j]; av[k] = bV[j]; }
    #pragma unroll 4
    for (int i = 0; i < 64; i++) {
        float wq = WQ[i * 64 + j], wk = WK[i * 64 + j], wv = WV[i * 64 + j];
        #pragma unroll
        for (int k = 0; k < 4; k++) {
            float hv = hs[nl + k][i];
            aq[k] += hv * wq; ak[k] += hv * wk; av[k] += hv * wv;
        }
    }
    float h0 = hopwise[0];
    #pragma unroll
    for (int k = 0; k < 4; k++) {
        int node = nbase + nl + k;
        if (node < n) {
            float q  = 1.f + ((aq[k] > 0.f) ? aq[k] : (expf(aq[k]) - 1.f));
            float kf = 1.f + ((ak[k] > 0.f) ? ak[k] : (expf(ak[k]) - 1.f));
            int dg = min(cnt[node], SLOTS);
            float inv = (dg > 0) ? 1.0f / (float)dg : 0.0f;
            Q[(size_t)node * 64 + j] = q;
            Kf0[(size_t)node * 64 + j] = f2bf(kf * inv);       // pre-scaled Kf'
            Vbuf[(size_t)node * 64 + j] = f2bf(av[k]);
            hidden[(size_t)node * 64 + j] = av[k] * h0;
        }
    }
}

// ---- hop 0 (LDS-staged outer product): 2 nodes/block, 128 thr/node.
// Per 4-edge group: coalesced 128B row loads of Kf'(bf16) and V(bf16) into
// LDS (one request per row per wave, zero redundancy), then each thread
// (h = gtid>>5, i = (gtid>>1)&15, jh = gtid&1) accumulates its 8-element
// outer-product slice from LDS broadcasts. Dense-style LDS epilogue.
__global__ __launch_bounds__(256) void k_hop0(
    const unsigned short* __restrict__ Kfold, const unsigned short* __restrict__ Vbuf,
    const int* __restrict__ cnt, const int* __restrict__ csr,
    const float* __restrict__ Q, const float* __restrict__ gamma,
    unsigned char* __restrict__ Mnew, unsigned short* __restrict__ Kfnew,
    float* __restrict__ hidden, int n) {
    int group = threadIdx.x >> 7;        // node slot within block (0/1)
    int gtid  = threadIdx.x & 127;       // thread within node group
    int node  = blockIdx.x * 2 + group;
    int off   = gtid * 8;                // this thread's 8 output elements
    int h   = gtid >> 5;                 // head
    int kfi = gtid >> 1;                 // h*16 + i
    int jh  = gtid & 1;
    __shared__ float skf[2][4][64];      // 2 KB  staged Kf' rows (f32)
    __shared__ float sv[2][4][64];       // 2 KB  staged V rows (f32)
    __shared__ float sm[2][MSZ];         // 8 KB  epilogue M accumulators
    __shared__ float sk[2][64];
    __shared__ int dmax_s;
    bool valid = (node < n);
    int deg = 0;
    const int* lst = nullptr;
    if (valid) {
        deg = min(cnt[node], SLOTS);
        lst = csr + (size_t)node * SLOTS;
    }
    if (threadIdx.x == 0) dmax_s = 0;
    __syncthreads();
    if (valid && gtid == 0) atomicMax(&dmax_s, deg);
    __syncthreads();
    int dmax = dmax_s;

    float acc[8];
    #pragma unroll
    for (int t = 0; t < 8; t++) acc[t] = 0.f;
    float kacc = 0.f;

    // staging role: p = edge within group (0..3), e2 = ushort2 index (0..31)
    int p = gtid >> 5, e2 = gtid & 31;
    for (int d0 = 0; d0 < dmax; d0 += 4) {
        if (valid && d0 + p < deg) {
            int s = lst[d0 + p];
            unsigned int kk = *(const unsigned int*)(Kfold + (size_t)s * 64 + e2 * 2);
            unsigned int vv = *(const unsigned int*)(Vbuf + (size_t)s * 64 + e2 * 2);
            skf[group][p][e2 * 2]     = bfu_lo(kk);
            skf[group][p][e2 * 2 + 1] = bfu_hi(kk);
            sv[group][p][e2 * 2]      = bfu_lo(vv);
            sv[group][p][e2 * 2 + 1]  = bfu_hi(vv);
        }
        __syncthreads();
        if (valid) {
            int lim = min(deg - d0, 4);              // uniform per node group
            for (int pp = 0; pp < lim; pp++) {
                float kf = skf[group][pp][kfi];
                kacc += kf;
                const float* vrow = &sv[group][pp][h * 16 + jh * 8];
                #pragma unroll
                for (int k = 0; k < 8; k++) acc[k] = fmaf(kf, vrow[k], acc[k]);
            }
        }
        __syncthreads();                             // protect staging buffers
    }

    if (valid) {
        // stage M contribution for epilogue + write M'/Kf'
        float4* dst = (float4*)&sm[group][off];
        dst[0] = make_float4(acc[0], acc[1], acc[2], acc[3]);
        dst[1] = make_float4(acc[4], acc[5], acc[6], acc[7]);
        if (jh == 0) sk[group][kfi] = kacc;
        float inv = (deg > 0) ? 1.0f / (float)deg : 0.0f;
        uint2 st;
        st.x = pack4fp8(acc[0] * inv, acc[1] * inv, acc[2] * inv, acc[3] * inv);
        st.y = pack4fp8(acc[4] * inv, acc[5] * inv, acc[6] * inv, acc[7] * inv);
        *(uint2*)(Mnew + (size_t)node * MSZ + off) = st;
        if (jh == 0) Kfnew[(size_t)node * 64 + kfi] = f2bf(kacc * inv);
    }
    __syncthreads();
    if (valid && gtid < 64) {
        int hh = gtid >> 4, j = gtid & 15;
        const float* qn = Q + (size_t)node * 64 + hh * 16;
        float C = CST, H = 0.f;
        #pragma unroll
        for (int i = 0; i < 16; i++) {
            float qv = qn[i];
            C += qv * sk[group][hh * 16 + i];
            H += qv * sm[group][hh * 256 + i * 16 + j];
        }
        float g = gamma[0 * HEADS + hh];
        size_t hoff = (size_t)node * 64 + gtid;
        hidden[hoff] = hidden[hoff] + g * H / C;
    }
}

// ---- dense hops 1,2 (R7/R13 structure): 2 nodes/block, 128 thr/node;
// 8B/lane, 4 edges/iter. LDS epilogue; low VGPR -> high occupancy.
// write_out=1: update hidden + write M'/Kf'. write_out=0: final — fused Wo
// projection (out16) + edge-head P1/P2 factorization into Pbuf.
__global__ __launch_bounds__(256) void k_dense(
    const unsigned char* __restrict__ Mold, const unsigned short* __restrict__ Kfold,
    const int* __restrict__ cnt, const int* __restrict__ csr,
    const float* __restrict__ Q, const float* __restrict__ gamma,
    unsigned char* __restrict__ Mnew, unsigned short* __restrict__ Kfnew,
    float* __restrict__ hidden, int hop, int write_out,
    const float* __restrict__ Wo, const float* __restrict__ bo,
    const float* __restrict__ Wf1, float* __restrict__ out16,
    float* __restrict__ Pbuf, int n) {
    int group = threadIdx.x >> 7;        // node slot within block (0/1)
    int gtid  = threadIdx.x & 127;       // thread within node group
    int node  = blockIdx.x * 2 + group;
    int off   = gtid * 8;                // this thread's 8 fp8 elements [off, off+8)
    __shared__ float sm[2][MSZ];         // 8 KB
    __shared__ float sk[2][64];
    __shared__ float sh[2][64];
    __shared__ float so[2][16];
    bool valid = (node < n);
    float acc[8];
    #pragma unroll
    for (int t = 0; t < 8; t++) acc[t] = 0.f;
    float kacc = 0.f;
    if (valid) {
        int deg = min(cnt[node], SLOTS);
        const int* lst = csr + (size_t)node * SLOTS;
        int d = 0;
        for (; d + 4 <= deg; d += 4) {
            int s0 = lst[d + 0], s1 = lst[d + 1], s2 = lst[d + 2], s3 = lst[d + 3];
            uint2 m0 = *(const uint2*)(Mold + (size_t)s0 * MSZ + off);
            uint2 m1 = *(const uint2*)(Mold + (size_t)s1 * MSZ + off);
            uint2 m2 = *(const uint2*)(Mold + (size_t)s2 * MSZ + off);
            uint2 m3 = *(const uint2*)(Mold + (size_t)s3 * MSZ + off);
            float kr0 = 0.f, kr1 = 0.f, kr2 = 0.f, kr3 = 0.f;
            if (gtid < 64) {
                kr0 = bf2f(Kfold[(size_t)s0 * 64 + gtid]);
                kr1 = bf2f(Kfold[(size_t)s1 * 64 + gtid]);
                kr2 = bf2f(Kfold[(size_t)s2 * 64 + gtid]);
                kr3 = bf2f(Kfold[(size_t)s3 * 64 + gtid]);
            }
            const uint2 mm[4] = {m0, m1, m2, m3};
            #pragma unroll
            for (int p = 0; p < 4; p++) {
                f32x2 q;
                q = __builtin_amdgcn_cvt_pk_f32_fp8((int)mm[p].x, false); acc[0] += q.x; acc[1] += q.y;
                q = __builtin_amdgcn_cvt_pk_f32_fp8((int)mm[p].x, true);  acc[2] += q.x; acc[3] += q.y;
                q = __builtin_amdgcn_cvt_pk_f32_fp8((int)mm[p].y, false); acc[4] += q.x; acc[5] += q.y;
                q = __builtin_amdgcn_cvt_pk_f32_fp8((int)mm[p].y, true);  acc[6] += q.x; acc[7] += q.y;
            }
            if (gtid < 64) kacc += (kr0 + kr1) + (kr2 + kr3);
        }
        for (; d < deg; d++) {
            int s = lst[d];
            uint2 mv = *(const uint2*)(Mold + (size_t)s * MSZ + off);
            f32x2 q;
            q = __builtin_amdgcn_cvt_pk_f32_fp8((int)mv.x, false); acc[0] += q.x; acc[1] += q.y;
            q = __builtin_amdgcn_cvt_pk_f32_fp8((int)mv.x, true);  acc[2] += q.x; acc[3] += q.y;
            q = __builtin_amdgcn_cvt_pk_f32_fp8((int)mv.y, false); acc[4] += q.x; acc[5] += q.y;
            q = __builtin_amdgcn_cvt_pk_f32_fp8((int)mv.y, true);  acc[6] += q.x; acc[7] += q.y;
            if (gtid < 64) kacc += bf2f(Kfold[(size_t)s * 64 + gtid]);
        }
        // stage + optional write-out
        float4* dst = (float4*)&sm[group][off];
        dst[0] = make_float4(acc[0], acc[1], acc[2], acc[3]);
        dst[1] = make_float4(acc[4], acc[5], acc[6], acc[7]);
        if (gtid < 64) sk[group][gtid] = kacc;
        if (write_out) {
            float inv = (deg > 0) ? 1.0f / (float)deg : 0.0f;
            uint2 st;
            st.x = pack4fp8(acc[0] * inv, acc[1] * inv, acc[2] * inv, acc[3] * inv);
            st.y = pack4fp8(acc[4] * inv, acc[5] * inv, acc[6] * inv, acc[7] * inv);
            *(uint2*)(Mnew + (size_t)node * MSZ + off) = st;
            if (gtid < 64) Kfnew[(size_t)node * 64 + gtid] = f2bf(kacc * inv);
        }
    }
    __syncthreads();
    if (valid && gtid < 64) {
        int hh = gtid >> 4, j = gtid & 15;
        const float* qn = Q + (size_t)node * 64 + hh * 16;
        float C = CST, H = 0.f;
        #pragma unroll
        for (int i = 0; i < 16; i++) {
            float qv = qn[i];
            C += qv * sk[group][hh * 16 + i];
            H += qv * sm[group][hh * 256 + i * 16 + j];
        }
        float g = gamma[hop * HEADS + hh];
        float hid = hidden[(size_t)node * 64 + gtid] + g * H / C;
        if (write_out) hidden[(size_t)node * 64 + gtid] = hid;
        else sh[group][gtid] = hid;              // final hop: feed fused projection
    }
    if (!write_out) {
        __syncthreads();
        if (valid && gtid < 16) {
            float a = bo[gtid];
            #pragma unroll 8
            for (int i = 0; i < 64; i++) a += sh[group][i] * Wo[i * 16 + gtid];
            out16[(size_t)node * 16 + gtid] = a;
            so[group][gtid] = a;
        }
        __syncthreads();
        if (valid && gtid < 32) {
            int o = gtid & 15, half = gtid >> 4;
            const float* wf = Wf1 + (size_t)(half * 16) * 16 + o;
            float p = 0.f;
            #pragma unroll
            for (int i = 0; i < 16; i++) p += so[group][i] * wf[i * 16];
            Pbuf[(size_t)node * 32 + gtid] = p;  // [n][0:16]=P1(src), [16:32]=P2(dst)
        }
    }
}

// ---------------- edge regression head: z = P1[s] + P2[d] + b1 ----------------
__global__ __launch_bounds__(256) void k_edge(
    const int* __restrict__ src, const int* __restrict__ dst,
    const float* __restrict__ Pbuf,
    const float* __restrict__ bf1, const float* __restrict__ Wf2,
    const float* __restrict__ bf2,
    float* __restrict__ out, int fe) {
    __shared__ float b1[16];
    __shared__ float w2[16];
    __shared__ float b2s;
    int t = threadIdx.x;
    if (t < 16) { b1[t] = bf1[t]; w2[t] = Wf2[t]; }
    if (t == 0) b2s = bf2[0];
    __syncthreads();
    int e = blockIdx.x * 256 + t;
    if (e >= fe) return;
    int s = src[e], d = dst[e];
    const float4* p1 = (const float4*)(Pbuf + (size_t)s * 32);
    const float4* p2 = (const float4*)(Pbuf + (size_t)d * 32 + 16);
    float z[16];
    #pragma unroll
    for (int q = 0; q < 4; q++) {
        float4 a = p1[q]; float4 b = p2[q];
        z[q * 4 + 0] = a.x + b.x; z[q * 4 + 1] = a.y + b.y;
        z[q * 4 + 2] = a.z + b.z; z[q * 4 + 3] = a.w + b.w;
    }
    float acc = b2s;
    #pragma unroll
    for (int o = 0; o < 16; o++) {
        float zz = z[o] + b1[o];
        zz = zz / (1.f + expf(-zz));       // silu
        acc += zz * w2[o];
    }
    out[e] = acc;
}

extern "C" void kernel_launch(void* const* d_in, const int* in_sizes, int n_in,
                              void* d_out, int out_size, void* d_ws, size_t ws_size,
                              hipStream_t stream) {
    const float* x        = (const float*)d_in[0];
    const int*   eidx     = (const int*)d_in[1];
    const int*   feidx    = (const int*)d_in[2];
    const int*   tsteps   = (const int*)d_in[3];
    const float* Wi  = (const float*)d_in[4];
    const float* bi  = (const float*)d_in[5];
    const float* Wt1 = (const float*)d_in[6];
    const float* bt1 = (const float*)d_in[7];
    const float* Wt2 = (const float*)d_in[8];
    const float* bt2 = (const float*)d_in[9];
    const float* WQ  = (const float*)d_in[10];
    const float* bQ  = (const float*)d_in[11];
    const float* WK  = (const float*)d_in[12];
    const float* bK  = (const float*)d_in[13];
    const float* WV  = (const float*)d_in[14];
    const float* bV  = (const float*)d_in[15];
    const float* Wo  = (const float*)d_in[16];
    const float* bo  = (const float*)d_in[17];
    const float* hopwise  = (const float*)d_in[18];
    const float* headwise = (const float*)d_in[19];
    const float* Wf1 = (const float*)d_in[20];
    const float* bf1 = (const float*)d_in[21];
    const float* Wf2 = (const float*)d_in[22];
    const float* bf2 = (const float*)d_in[23];

    const int N  = in_sizes[3];
    const int E  = in_sizes[1] / 2;
    const int FE = in_sizes[2] / 2;
    const int* row = eidx;           // [0,:]
    const int* col = eidx + E;       // [1,:]
    const int* fsrc = feidx;
    const int* fdst = feidx + FE;

    // ---- workspace carve-up (256B aligned) ----
    char* ws = (char*)d_ws;
    size_t off = 0;
    auto alloc = [&](size_t bytes) -> char* {
        char* p = ws + off;
        off = (off + bytes + 255) & ~(size_t)255;
        return p;
    };
    float* gamma     = (float*)alloc(KHOP * HEADS * sizeof(float));
    int*   cnt       = (int*)alloc((size_t)N * 4);
    int*   csr       = (int*)alloc((size_t)N * SLOTS * 4);
    float* temb      = (float*)alloc((size_t)NUM_T * HC * 4);
    float* Qbuf      = (float*)alloc((size_t)N * HC * 4);
    unsigned short* Kf0  = (unsigned short*)alloc((size_t)N * HC * 2);
    unsigned short* Kf_a = (unsigned short*)alloc((size_t)N * HC * 2);
    unsigned short* Kf_b = (unsigned short*)alloc((size_t)N * HC * 2);
    unsigned short* Vbuf = (unsigned short*)alloc((size_t)N * HC * 2);
    float* hidden    = (float*)alloc((size_t)N * HC * 4);
    unsigned char* M_a = (unsigned char*)alloc((size_t)N * MSZ);
    unsigned char* M_b = (unsigned char*)alloc((size_t)N * MSZ);
    float* Pbuf      = (float*)alloc((size_t)N * 32 * 4);
    (void)ws_size;

    float* out_edges = (float*)d_out;            // [FE]
    float* out_hid16 = (float*)d_out + FE;       // [N,16]

    const int fillBlocks = (E + 255) / 256;
    const int preBlocks  = fillBlocks + NUM_T;
    const int hopBlocks  = (N + 1) / 2;

    (void)hipMemsetAsync(cnt, 0, (size_t)N * 4, stream);
    // fused: CSR fill + temb table + gamma (one dispatch)
    k_pre<<<preBlocks, 256, 0, stream>>>(row, col, cnt, csr, E, fillBlocks,
                                         Wt1, bt1, Wt2, bt2, hopwise, headwise,
                                         gamma, temb);
    k_node<<<(N + 15) / 16, 256, 0, stream>>>(x, tsteps, temb, Wi, bi,
                                              WQ, bQ, WK, bK, WV, bV, hopwise, cnt,
                                              Qbuf, Kf0, Vbuf, hidden, N);
    // hop 0 (LDS-staged outer product): -> M_a', Kf_a'
    k_hop0<<<hopBlocks, 256, 0, stream>>>(Kf0, Vbuf, cnt, csr, Qbuf, gamma,
                                          M_a, Kf_a, hidden, N);
    // hop 1 (dense): M_a' -> M_b'
    k_dense<<<hopBlocks, 256, 0, stream>>>(M_a, Kf_a, cnt, csr, Qbuf, gamma,
                                           M_b, Kf_b, hidden, 1, 1, Wo, bo, Wf1,
                                           out_hid16, Pbuf, N);
    // hop 2 (dense, final): gather M_b', fused Wo projection + P1/P2
    k_dense<<<hopBlocks, 256, 0, stream>>>(M_b, Kf_b, cnt, csr, Qbuf, gamma,
                                           M_a, Kf_a, hidden, 2, 0, Wo, bo, Wf1,
                                           out_hid16, Pbuf, N);
    k_edge<<<(FE + 255) / 256, 256, 0, stream>>>(fsrc, fdst, Pbuf, bf1, Wf2, bf2,
                                                 out_edges, FE);
}

// Round 10
// 255.847 us; speedup vs baseline: 1.0200x; 1.0087x over previous
//
#include <hip/hip_runtime.h>
#include <math.h>

// MSTAGNN: N nodes, E edges (propagation), FE full edges (regression head).
// HC=64, HEADS=4, HEADC=DV=16, KHOP=3, NUM_T=128.
// R16 = exact R13 (best verified, 251.5us): dense hops in the 2-node/block,
// 128-thr/node, 32-VGPR, ~67%-occ R7 structure (pinned at the ~2 TB/s
// scattered-miss wall, 83.4 MB/hop — 7 structures tried); hop 0 in the
// wave-per-node readlane-pipelined form (best of 3 hop0 variants: R14
// redundant-request version +10us, R15 LDS-barrier version +6us);
// fused final-hop epilogue (Wo projection + edge-head P1/P2 factorization).

#define HC 64
#define HEADS 4
#define KHOP 3
#define NUM_T 128
#define MSZ 1024    // bytes per node M row (fp8)
#define SLOTS 64    // padded CSR slots per node
#define CST 1e-5f

typedef float f32x2 __attribute__((ext_vector_type(2)));

// ---- bf16 helpers (storage-only precision; accumulate in fp32) ----
__device__ __forceinline__ float bf2f(unsigned short s) { return __uint_as_float(((unsigned int)s) << 16); }
__device__ __forceinline__ float bfu_lo(unsigned int u) { return __uint_as_float(u << 16); }
__device__ __forceinline__ float bfu_hi(unsigned int u) { return __uint_as_float(u & 0xffff0000u); }
__device__ __forceinline__ unsigned short f2bf(float f) {
    unsigned int u = __float_as_uint(f);
    u = (u + 0x7fffu + ((u >> 16) & 1u)) >> 16;   // RTNE
    return (unsigned short)u;
}
// ---- fp8 e4m3 via HW pack/unpack (gfx950 OCP) ----
__device__ __forceinline__ unsigned int pack4fp8(float a, float b, float c, float d) {
    int r = __builtin_amdgcn_cvt_pk_fp8_f32(a, b, 0, false);       // bytes 0,1
    r = __builtin_amdgcn_cvt_pk_fp8_f32(c, d, r, true);            // bytes 2,3
    return (unsigned int)r;
}

// ---- k_pre: blocks [0,fillBlocks) = padded-CSR fill; blocks [fillBlocks,
//      fillBlocks+NUM_T) = temb table (one tval each) + gamma (first) ----
__global__ __launch_bounds__(256) void k_pre(
    const int* __restrict__ row, const int* __restrict__ col,
    int* __restrict__ cnt, int* __restrict__ csr, int E, int fillBlocks,
    const float* __restrict__ Wt1, const float* __restrict__ bt1,
    const float* __restrict__ Wt2, const float* __restrict__ bt2,
    const float* __restrict__ hopwise, const float* __restrict__ headwise,
    float* __restrict__ gamma, float* __restrict__ table) {
    int b = blockIdx.x;
    if (b < fillBlocks) {
        int e = b * 256 + threadIdx.x;
        if (e < E) {
            int c = col[e];
            int r = row[e];
            int k = atomicAdd(&cnt[c], 1);
            if (k < SLOTS) csr[c * SLOTS + k] = r;
        }
        return;
    }
    int tval = b - fillBlocks;                       // 0..127
    int t = threadIdx.x;
    if (tval == 0 && t == 0) {
        for (int k = 0; k < KHOP; k++) {
            float m = -1e30f;
            for (int h2 = 0; h2 < HEADS; h2++) m = fmaxf(m, headwise[h2 * KHOP + k]);
            float ex[HEADS]; float s = 0.f;
            for (int h2 = 0; h2 < HEADS; h2++) { ex[h2] = expf(headwise[h2 * KHOP + k] - m); s += ex[h2]; }
            for (int h2 = 0; h2 < HEADS; h2++) gamma[k * HEADS + h2] = hopwise[k + 1] * ex[h2] / s;
        }
    }
    __shared__ float emb_s[64];
    __shared__ float z1_s[256];
    __shared__ float ps_s[4][64];
    if (t < 64) {
        float tt = (float)tval * 31.25f;             // 4000/128
        float e;
        if (t < 32) e = sinf(tt * expf(-0.2971077539347156f * (float)t));
        else        e = cosf(tt * expf(-0.2971077539347156f * (float)(t - 32)));
        emb_s[t] = e;
    }
    __syncthreads();
    {   // z1[t] = silu(emb . Wt1[:,t] + bt1[t])
        float acc = bt1[t];
        #pragma unroll 8
        for (int i = 0; i < 64; i++) acc += emb_s[i] * Wt1[i * 256 + t];
        z1_s[t] = acc / (1.f + expf(-acc));
    }
    __syncthreads();
    {   // out[j] = z1 . Wt2[:,j] + bt2[j], split over 4 partials
        int j = t & 63, p = t >> 6;
        float acc = 0.f;
        #pragma unroll 8
        for (int i = 0; i < 64; i++) acc += z1_s[p * 64 + i] * Wt2[(p * 64 + i) * 64 + j];
        ps_s[p][j] = acc;
    }
    __syncthreads();
    if (t < 64)
        table[tval * 64 + t] = ps_s[0][t] + ps_s[1][t] + ps_s[2][t] + ps_s[3][t] + bt2[t];
}

// ---- fused node kernel: h -> QKV -> Q, pre-scaled Kf0'(bf16), V(bf16),
//      hidden init. inv_deg computed from cnt in-register. ----
__global__ __launch_bounds__(256) void k_node(
    const float* __restrict__ x, const int* __restrict__ time_steps,
    const float* __restrict__ temb, const float* __restrict__ Wi,
    const float* __restrict__ bi,
    const float* __restrict__ WQ, const float* __restrict__ bQ,
    const float* __restrict__ WK, const float* __restrict__ bK,
    const float* __restrict__ WV, const float* __restrict__ bV,
    const float* __restrict__ hopwise, const int* __restrict__ cnt,
    float* __restrict__ Q, unsigned short* __restrict__ Kf0,
    unsigned short* __restrict__ Vbuf, float* __restrict__ hidden, int n) {
    __shared__ float xs[16][128];                      // 8 KB
    __shared__ float hs[16][64];                       // 4 KB
    int j = threadIdx.x & 63;
    int slot = threadIdx.x >> 6;                       // wave id
    int nbase = blockIdx.x * 16;
    int nvalid = min(16, n - nbase);
    const float4* xg = (const float4*)(x + (size_t)nbase * 128);
    float4* xs4 = (float4*)&xs[0][0];
    for (int idx = threadIdx.x; idx < nvalid * 32; idx += 256) xs4[idx] = xg[idx];
    __syncthreads();
    int nl = slot * 4;
    {
        float acc[4];
        #pragma unroll
        for (int k = 0; k < 4; k++) acc[k] = 0.f;
        #pragma unroll 8
        for (int i = 0; i < 128; i++) {
            float w = Wi[i * 64 + j];
            #pragma unroll
            for (int k = 0; k < 4; k++) acc[k] += xs[nl + k][i] * w;
        }
        float bj = bi[j];
        #pragma unroll
        for (int k = 0; k < 4; k++) {
            int node = nbase + nl + k;
            float te = (node < n) ? temb[time_steps[node] * 64 + j] : 0.f;
            hs[nl + k][j] = fmaxf(acc[k] + bj + te, 0.f);
        }
    }
    __syncthreads();
    float aq[4], ak[4], av[4];
    #pragma unroll
    for (int k = 0; k < 4; k++) { aq[k] = bQ[j]; ak[k] = bK[j]; av[k] = bV[j]; }
    #pragma unroll 4
    for (int i = 0; i < 64; i++) {
        float wq = WQ[i * 64 + j], wk = WK[i * 64 + j], wv = WV[i * 64 + j];
        #pragma unroll
        for (int k = 0; k < 4; k++) {
            float hv = hs[nl + k][i];
            aq[k] += hv * wq; ak[k] += hv * wk; av[k] += hv * wv;
        }
    }
    float h0 = hopwise[0];
    #pragma unroll
    for (int k = 0; k < 4; k++) {
        int node = nbase + nl + k;
        if (node < n) {
            float q  = 1.f + ((aq[k] > 0.f) ? aq[k] : (expf(aq[k]) - 1.f));
            float kf = 1.f + ((ak[k] > 0.f) ? ak[k] : (expf(ak[k]) - 1.f));
            int dg = min(cnt[node], SLOTS);
            float inv = (dg > 0) ? 1.0f / (float)dg : 0.0f;
            Q[(size_t)node * 64 + j] = q;
            Kf0[(size_t)node * 64 + j] = f2bf(kf * inv);       // pre-scaled Kf'
            Vbuf[(size_t)node * 64 + j] = f2bf(av[k]);
            hidden[(size_t)node * 64 + j] = av[k] * h0;
        }
    }
}

// ---- hop 0: wave-per-node outer-product gather from Kf'(bf16) + V(bf16).
// No LDS, no barriers; 2 nodes/block (128 thr). Always writes M'/Kf'/hidden.
__global__ __launch_bounds__(128) void k_hop0(
    const unsigned short* __restrict__ Kfold, const unsigned short* __restrict__ Vbuf,
    const int* __restrict__ cnt, const int* __restrict__ csr,
    const float* __restrict__ Q, const float* __restrict__ gamma,
    unsigned char* __restrict__ Mnew, unsigned short* __restrict__ Kfnew,
    float* __restrict__ hidden, int n) {
    constexpr int DEPTH = 4;
    int lane = threadIdx.x & 63;
    int node = blockIdx.x * 2 + (threadIdx.x >> 6);
    if (node >= n) return;
    int grp = lane >> 4;                               // head h
    int deg = min(cnt[node], SLOTS);
    int sidx = csr[(size_t)node * SLOTS + lane];       // all 64 slots, one load
    float qv = Q[(size_t)node * 64 + lane];
    size_t hoff = (size_t)node * 64 + lane;
    float hid_in = hidden[hoff];
    int degU = __builtin_amdgcn_readfirstlane(deg);
    float acc[16];
    #pragma unroll
    for (int t = 0; t < 16; t++) acc[t] = 0.f;
    float kacc = 0.f;

    int d = 0;
    for (; d + DEPTH <= degU; d += DEPTH) {
        unsigned short kraw[DEPTH];
        uint4 m0[DEPTH], m1[DEPTH];
        #pragma unroll
        for (int t = 0; t < DEPTH; t++) {
            int s = __builtin_amdgcn_readlane(sidx, d + t);   // SGPR base
            kraw[t] = Kfold[(size_t)s * 64 + lane];
            const uint4* vp = (const uint4*)((const unsigned char*)Vbuf + (size_t)s * 128 + grp * 32);
            m0[t] = vp[0]; m1[t] = vp[1];
        }
        #pragma unroll
        for (int t = 0; t < DEPTH; t++) {
            float kf = bf2f(kraw[t]);
            kacc += kf;
            acc[0]  = fmaf(kf, bfu_lo(m0[t].x), acc[0]);
            acc[1]  = fmaf(kf, bfu_hi(m0[t].x), acc[1]);
            acc[2]  = fmaf(kf, bfu_lo(m0[t].y), acc[2]);
            acc[3]  = fmaf(kf, bfu_hi(m0[t].y), acc[3]);
            acc[4]  = fmaf(kf, bfu_lo(m0[t].z), acc[4]);
            acc[5]  = fmaf(kf, bfu_hi(m0[t].z), acc[5]);
            acc[6]  = fmaf(kf, bfu_lo(m0[t].w), acc[6]);
            acc[7]  = fmaf(kf, bfu_hi(m0[t].w), acc[7]);
            acc[8]  = fmaf(kf, bfu_lo(m1[t].x), acc[8]);
            acc[9]  = fmaf(kf, bfu_hi(m1[t].x), acc[9]);
            acc[10] = fmaf(kf, bfu_lo(m1[t].y), acc[10]);
            acc[11] = fmaf(kf, bfu_hi(m1[t].y), acc[11]);
            acc[12] = fmaf(kf, bfu_lo(m1[t].z), acc[12]);
            acc[13] = fmaf(kf, bfu_hi(m1[t].z), acc[13]);
            acc[14] = fmaf(kf, bfu_lo(m1[t].w), acc[14]);
            acc[15] = fmaf(kf, bfu_hi(m1[t].w), acc[15]);
        }
    }
    if (d < degU) {
        int rem = degU - d;                            // 1..DEPTH-1
        unsigned short kraw[DEPTH];
        uint4 m0[DEPTH], m1[DEPTH];
        #pragma unroll
        for (int t = 0; t < DEPTH - 1; t++) {
            if (t < rem) {
                int s = __builtin_amdgcn_readlane(sidx, d + t);
                kraw[t] = Kfold[(size_t)s * 64 + lane];
                const uint4* vp = (const uint4*)((const unsigned char*)Vbuf + (size_t)s * 128 + grp * 32);
                m0[t] = vp[0]; m1[t] = vp[1];
            }
        }
        #pragma unroll
        for (int t = 0; t < DEPTH - 1; t++) {
            if (t < rem) {
                float kf = bf2f(kraw[t]);
                kacc += kf;
                acc[0]  = fmaf(kf, bfu_lo(m0[t].x), acc[0]);
                acc[1]  = fmaf(kf, bfu_hi(m0[t].x), acc[1]);
                acc[2]  = fmaf(kf, bfu_lo(m0[t].y), acc[2]);
                acc[3]  = fmaf(kf, bfu_hi(m0[t].y), acc[3]);
                acc[4]  = fmaf(kf, bfu_lo(m0[t].z), acc[4]);
                acc[5]  = fmaf(kf, bfu_hi(m0[t].z), acc[5]);
                acc[6]  = fmaf(kf, bfu_lo(m0[t].w), acc[6]);
                acc[7]  = fmaf(kf, bfu_hi(m0[t].w), acc[7]);
                acc[8]  = fmaf(kf, bfu_lo(m1[t].x), acc[8]);
                acc[9]  = fmaf(kf, bfu_hi(m1[t].x), acc[9]);
                acc[10] = fmaf(kf, bfu_lo(m1[t].y), acc[10]);
                acc[11] = fmaf(kf, bfu_hi(m1[t].y), acc[11]);
                acc[12] = fmaf(kf, bfu_lo(m1[t].z), acc[12]);
                acc[13] = fmaf(kf, bfu_hi(m1[t].z), acc[13]);
                acc[14] = fmaf(kf, bfu_lo(m1[t].w), acc[14]);
                acc[15] = fmaf(kf, bfu_hi(m1[t].w), acc[15]);
            }
        }
    }

    {   // write M'/Kf' (pre-scaled by own in-degree)
        float inv = (degU > 0) ? 1.0f / (float)degU : 0.0f;
        uint4 st;
        st.x = pack4fp8(acc[0] * inv,  acc[1] * inv,  acc[2] * inv,  acc[3] * inv);
        st.y = pack4fp8(acc[4] * inv,  acc[5] * inv,  acc[6] * inv,  acc[7] * inv);
        st.z = pack4fp8(acc[8] * inv,  acc[9] * inv,  acc[10] * inv, acc[11] * inv);
        st.w = pack4fp8(acc[12] * inv, acc[13] * inv, acc[14] * inv, acc[15] * inv);
        *(uint4*)(Mnew + (size_t)node * MSZ + lane * 16) = st;
        Kfnew[(size_t)node * 64 + lane] = f2bf(kacc * inv);
    }

    // C[h] allreduce within head group
    float c = qv * kacc;
    c += __shfl_xor(c, 1); c += __shfl_xor(c, 2); c += __shfl_xor(c, 4); c += __shfl_xor(c, 8);

    // H[h,j] reduce-scatter over the 16 i-lanes (lane (h,i) ends with H[h,j=i])
    float w0[16];
    #pragma unroll
    for (int t = 0; t < 16; t++) w0[t] = qv * acc[t];
    float w1r[8];
    #pragma unroll
    for (int t = 0; t < 8; t++) {
        float a = w0[2 * t], b = w0[2 * t + 1];
        float mine = (lane & 1) ? b : a, th = (lane & 1) ? a : b;
        w1r[t] = mine + __shfl_xor(th, 1);
    }
    float w2r[4];
    #pragma unroll
    for (int t = 0; t < 4; t++) {
        float a = w1r[2 * t], b = w1r[2 * t + 1];
        float mine = (lane & 2) ? b : a, th = (lane & 2) ? a : b;
        w2r[t] = mine + __shfl_xor(th, 2);
    }
    float w3r[2];
    #pragma unroll
    for (int t = 0; t < 2; t++) {
        float a = w2r[2 * t], b = w2r[2 * t + 1];
        float mine = (lane & 4) ? b : a, th = (lane & 4) ? a : b;
        w3r[t] = mine + __shfl_xor(th, 4);
    }
    float Hv;
    {
        float a = w3r[0], b = w3r[1];
        float mine = (lane & 8) ? b : a, th = (lane & 8) ? a : b;
        Hv = mine + __shfl_xor(th, 8);
    }

    float g = gamma[0 * HEADS + grp];
    hidden[hoff] = hid_in + g * Hv / (c + CST);
}

// ---- dense hops 1,2 (R7 structure): 2 nodes/block, 128 thr/node; 8B/lane,
// 4 edges/iter (32B/thread in flight). LDS epilogue; low VGPR -> high occ.
// write_out=1: update hidden + write M'/Kf'. write_out=0: final — fused Wo
// projection (out16) + edge-head P1/P2 factorization into Pbuf.
__global__ __launch_bounds__(256) void k_dense(
    const unsigned char* __restrict__ Mold, const unsigned short* __restrict__ Kfold,
    const int* __restrict__ cnt, const int* __restrict__ csr,
    const float* __restrict__ Q, const float* __restrict__ gamma,
    unsigned char* __restrict__ Mnew, unsigned short* __restrict__ Kfnew,
    float* __restrict__ hidden, int hop, int write_out,
    const float* __restrict__ Wo, const float* __restrict__ bo,
    const float* __restrict__ Wf1, float* __restrict__ out16,
    float* __restrict__ Pbuf, int n) {
    int group = threadIdx.x >> 7;        // node slot within block (0/1)
    int gtid  = threadIdx.x & 127;       // thread within node group
    int node  = blockIdx.x * 2 + group;
    int off   = gtid * 8;                // this thread's 8 fp8 elements [off, off+8)
    __shared__ float sm[2][MSZ];         // 8 KB
    __shared__ float sk[2][64];
    __shared__ float sh[2][64];
    __shared__ float so[2][16];
    bool valid = (node < n);
    float acc[8];
    #pragma unroll
    for (int t = 0; t < 8; t++) acc[t] = 0.f;
    float kacc = 0.f;
    if (valid) {
        int deg = min(cnt[node], SLOTS);
        const int* lst = csr + (size_t)node * SLOTS;
        int d = 0;
        for (; d + 4 <= deg; d += 4) {
            int s0 = lst[d + 0], s1 = lst[d + 1], s2 = lst[d + 2], s3 = lst[d + 3];
            uint2 m0 = *(const uint2*)(Mold + (size_t)s0 * MSZ + off);
            uint2 m1 = *(const uint2*)(Mold + (size_t)s1 * MSZ + off);
            uint2 m2 = *(const uint2*)(Mold + (size_t)s2 * MSZ + off);
            uint2 m3 = *(const uint2*)(Mold + (size_t)s3 * MSZ + off);
            float kr0 = 0.f, kr1 = 0.f, kr2 = 0.f, kr3 = 0.f;
            if (gtid < 64) {
                kr0 = bf2f(Kfold[(size_t)s0 * 64 + gtid]);
                kr1 = bf2f(Kfold[(size_t)s1 * 64 + gtid]);
                kr2 = bf2f(Kfold[(size_t)s2 * 64 + gtid]);
                kr3 = bf2f(Kfold[(size_t)s3 * 64 + gtid]);
            }
            const uint2 mm[4] = {m0, m1, m2, m3};
            #pragma unroll
            for (int p = 0; p < 4; p++) {
                f32x2 q;
                q = __builtin_amdgcn_cvt_pk_f32_fp8((int)mm[p].x, false); acc[0] += q.x; acc[1] += q.y;
                q = __builtin_amdgcn_cvt_pk_f32_fp8((int)mm[p].x, true);  acc[2] += q.x; acc[3] += q.y;
                q = __builtin_amdgcn_cvt_pk_f32_fp8((int)mm[p].y, false); acc[4] += q.x; acc[5] += q.y;
                q = __builtin_amdgcn_cvt_pk_f32_fp8((int)mm[p].y, true);  acc[6] += q.x; acc[7] += q.y;
            }
            if (gtid < 64) kacc += (kr0 + kr1) + (kr2 + kr3);
        }
        for (; d < deg; d++) {
            int s = lst[d];
            uint2 mv = *(const uint2*)(Mold + (size_t)s * MSZ + off);
            f32x2 q;
            q = __builtin_amdgcn_cvt_pk_f32_fp8((int)mv.x, false); acc[0] += q.x; acc[1] += q.y;
            q = __builtin_amdgcn_cvt_pk_f32_fp8((int)mv.x, true);  acc[2] += q.x; acc[3] += q.y;
            q = __builtin_amdgcn_cvt_pk_f32_fp8((int)mv.y, false); acc[4] += q.x; acc[5] += q.y;
            q = __builtin_amdgcn_cvt_pk_f32_fp8((int)mv.y, true);  acc[6] += q.x; acc[7] += q.y;
            if (gtid < 64) kacc += bf2f(Kfold[(size_t)s * 64 + gtid]);
        }
        // stage + optional write-out
        float4* dst = (float4*)&sm[group][off];
        dst[0] = make_float4(acc[0], acc[1], acc[2], acc[3]);
        dst[1] = make_float4(acc[4], acc[5], acc[6], acc[7]);
        if (gtid < 64) sk[group][gtid] = kacc;
        if (write_out) {
            float inv = (deg > 0) ? 1.0f / (float)deg : 0.0f;
            uint2 st;
            st.x = pack4fp8(acc[0] * inv, acc[1] * inv, acc[2] * inv, acc[3] * inv);
            st.y = pack4fp8(acc[4] * inv, acc[5] * inv, acc[6] * inv, acc[7] * inv);
            *(uint2*)(Mnew + (size_t)node * MSZ + off) = st;
            if (gtid < 64) Kfnew[(size_t)node * 64 + gtid] = f2bf(kacc * inv);
        }
    }
    __syncthreads();
    if (valid && gtid < 64) {
        int hh = gtid >> 4, j = gtid & 15;
        const float* qn = Q + (size_t)node * 64 + hh * 16;
        float C = CST, H = 0.f;
        #pragma unroll
        for (int i = 0; i < 16; i++) {
            float qv = qn[i];
            C += qv * sk[group][hh * 16 + i];
            H += qv * sm[group][hh * 256 + i * 16 + j];
        }
        float g = gamma[hop * HEADS + hh];
        float hid = hidden[(size_t)node * 64 + gtid] + g * H / C;
        if (write_out) hidden[(size_t)node * 64 + gtid] = hid;
        else sh[group][gtid] = hid;              // final hop: feed fused projection
    }
    if (!write_out) {
        __syncthreads();
        if (valid && gtid < 16) {
            float a = bo[gtid];
            #pragma unroll 8
            for (int i = 0; i < 64; i++) a += sh[group][i] * Wo[i * 16 + gtid];
            out16[(size_t)node * 16 + gtid] = a;
            so[group][gtid] = a;
        }
        __syncthreads();
        if (valid && gtid < 32) {
            int o = gtid & 15, half = gtid >> 4;
            const float* wf = Wf1 + (size_t)(half * 16) * 16 + o;
            float p = 0.f;
            #pragma unroll
            for (int i = 0; i < 16; i++) p += so[group][i] * wf[i * 16];
            Pbuf[(size_t)node * 32 + gtid] = p;  // [n][0:16]=P1(src), [16:32]=P2(dst)
        }
    }
}

// ---------------- edge regression head: z = P1[s] + P2[d] + b1 ----------------
__global__ __launch_bounds__(256) void k_edge(
    const int* __restrict__ src, const int* __restrict__ dst,
    const float* __restrict__ Pbuf,
    const float* __restrict__ bf1, const float* __restrict__ Wf2,
    const float* __restrict__ bf2,
    float* __restrict__ out, int fe) {
    __shared__ float b1[16];
    __shared__ float w2[16];
    __shared__ float b2s;
    int t = threadIdx.x;
    if (t < 16) { b1[t] = bf1[t]; w2[t] = Wf2[t]; }
    if (t == 0) b2s = bf2[0];
    __syncthreads();
    int e = blockIdx.x * 256 + t;
    if (e >= fe) return;
    int s = src[e], d = dst[e];
    const float4* p1 = (const float4*)(Pbuf + (size_t)s * 32);
    const float4* p2 = (const float4*)(Pbuf + (size_t)d * 32 + 16);
    float z[16];
    #pragma unroll
    for (int q = 0; q < 4; q++) {
        float4 a = p1[q]; float4 b = p2[q];
        z[q * 4 + 0] = a.x + b.x; z[q * 4 + 1] = a.y + b.y;
        z[q * 4 + 2] = a.z + b.z; z[q * 4 + 3] = a.w + b.w;
    }
    float acc = b2s;
    #pragma unroll
    for (int o = 0; o < 16; o++) {
        float zz = z[o] + b1[o];
        zz = zz / (1.f + expf(-zz));       // silu
        acc += zz * w2[o];
    }
    out[e] = acc;
}

extern "C" void kernel_launch(void* const* d_in, const int* in_sizes, int n_in,
                              void* d_out, int out_size, void* d_ws, size_t ws_size,
                              hipStream_t stream) {
    const float* x        = (const float*)d_in[0];
    const int*   eidx     = (const int*)d_in[1];
    const int*   feidx    = (const int*)d_in[2];
    const int*   tsteps   = (const int*)d_in[3];
    const float* Wi  = (const float*)d_in[4];
    const float* bi  = (const float*)d_in[5];
    const float* Wt1 = (const float*)d_in[6];
    const float* bt1 = (const float*)d_in[7];
    const float* Wt2 = (const float*)d_in[8];
    const float* bt2 = (const float*)d_in[9];
    const float* WQ  = (const float*)d_in[10];
    const float* bQ  = (const float*)d_in[11];
    const float* WK  = (const float*)d_in[12];
    const float* bK  = (const float*)d_in[13];
    const float* WV  = (const float*)d_in[14];
    const float* bV  = (const float*)d_in[15];
    const float* Wo  = (const float*)d_in[16];
    const float* bo  = (const float*)d_in[17];
    const float* hopwise  = (const float*)d_in[18];
    const float* headwise = (const float*)d_in[19];
    const float* Wf1 = (const float*)d_in[20];
    const float* bf1 = (const float*)d_in[21];
    const float* Wf2 = (const float*)d_in[22];
    const float* bf2 = (const float*)d_in[23];

    const int N  = in_sizes[3];
    const int E  = in_sizes[1] / 2;
    const int FE = in_sizes[2] / 2;
    const int* row = eidx;           // [0,:]
    const int* col = eidx + E;       // [1,:]
    const int* fsrc = feidx;
    const int* fdst = feidx + FE;

    // ---- workspace carve-up (256B aligned) ----
    char* ws = (char*)d_ws;
    size_t off = 0;
    auto alloc = [&](size_t bytes) -> char* {
        char* p = ws + off;
        off = (off + bytes + 255) & ~(size_t)255;
        return p;
    };
    float* gamma     = (float*)alloc(KHOP * HEADS * sizeof(float));
    int*   cnt       = (int*)alloc((size_t)N * 4);
    int*   csr       = (int*)alloc((size_t)N * SLOTS * 4);
    float* temb      = (float*)alloc((size_t)NUM_T * HC * 4);
    float* Qbuf      = (float*)alloc((size_t)N * HC * 4);
    unsigned short* Kf0  = (unsigned short*)alloc((size_t)N * HC * 2);
    unsigned short* Kf_a = (unsigned short*)alloc((size_t)N * HC * 2);
    unsigned short* Kf_b = (unsigned short*)alloc((size_t)N * HC * 2);
    unsigned short* Vbuf = (unsigned short*)alloc((size_t)N * HC * 2);
    float* hidden    = (float*)alloc((size_t)N * HC * 4);
    unsigned char* M_a = (unsigned char*)alloc((size_t)N * MSZ);
    unsigned char* M_b = (unsigned char*)alloc((size_t)N * MSZ);
    float* Pbuf      = (float*)alloc((size_t)N * 32 * 4);
    (void)ws_size;

    float* out_edges = (float*)d_out;            // [FE]
    float* out_hid16 = (float*)d_out + FE;       // [N,16]

    const int fillBlocks = (E + 255) / 256;
    const int preBlocks  = fillBlocks + NUM_T;
    const int hopBlocks  = (N + 1) / 2;

    (void)hipMemsetAsync(cnt, 0, (size_t)N * 4, stream);
    // fused: CSR fill + temb table + gamma (one dispatch)
    k_pre<<<preBlocks, 256, 0, stream>>>(row, col, cnt, csr, E, fillBlocks,
                                         Wt1, bt1, Wt2, bt2, hopwise, headwise,
                                         gamma, temb);
    k_node<<<(N + 15) / 16, 256, 0, stream>>>(x, tsteps, temb, Wi, bi,
                                              WQ, bQ, WK, bK, WV, bV, hopwise, cnt,
                                              Qbuf, Kf0, Vbuf, hidden, N);
    // hop 0: outer-product gather (Kf0', V) -> M_a', Kf_a'
    k_hop0<<<hopBlocks, 128, 0, stream>>>(Kf0, Vbuf, cnt, csr, Qbuf, gamma,
                                          M_a, Kf_a, hidden, N);
    // hop 1 (dense, R7 structure): M_a' -> M_b'
    k_dense<<<hopBlocks, 256, 0, stream>>>(M_a, Kf_a, cnt, csr, Qbuf, gamma,
                                           M_b, Kf_b, hidden, 1, 1, Wo, bo, Wf1,
                                           out_hid16, Pbuf, N);
    // hop 2 (dense, final): gather M_b', fused Wo projection + P1/P2
    k_dense<<<hopBlocks, 256, 0, stream>>>(M_b, Kf_b, cnt, csr, Qbuf, gamma,
                                           M_a, Kf_a, hidden, 2, 0, Wo, bo, Wf1,
                                           out_hid16, Pbuf, N);
    k_edge<<<(FE + 255) / 256, 256, 0, stream>>>(fsrc, fdst, Pbuf, bf1, Wf2, bf2,
                                                 out_edges, FE);
}